// Round 4
// baseline (356.672 us; speedup 1.0000x reference)
//
#include <hip/hip_runtime.h>
#include <hip/hip_bf16.h>

#define DM 1024
#define NH 16
#define DKK 64
#define NB 2
#define SQL 2048
#define SKL 2048

typedef __attribute__((ext_vector_type(8))) short short8;
typedef __attribute__((ext_vector_type(4))) float floatx4;

static __device__ inline floatx4 mfma16(short8 a, short8 b, floatx4 c) {
    return __builtin_amdgcn_mfma_f32_16x16x32_bf16(a, b, c, 0, 0, 0);
}

static __device__ inline unsigned short f2bf(float f) {
    union { float f; unsigned int u; } x; x.f = f;
    unsigned int u = x.u;
    unsigned int r = (u + 0x7fff + ((u >> 16) & 1)) >> 16;
    return (unsigned short)r;
}

// async global(16B/lane) -> LDS (linear, wave-uniform base + lane*16)
__device__ __forceinline__ void gload16(const void* g, void* l) {
    __builtin_amdgcn_global_load_lds(
        (const __attribute__((address_space(1))) void*)g,
        (__attribute__((address_space(3))) void*)l, 16, 0, 0);
}

// ---------------- fp32 -> bf16 conversion of Q/K/V inputs ----------------
__global__ __launch_bounds__(256) void x2bf(
    const float* __restrict__ q, const float* __restrict__ k, const float* __restrict__ v,
    unsigned short* __restrict__ oq, unsigned short* __restrict__ ok, unsigned short* __restrict__ ov)
{
    const int n4 = 1 << 20;  // float4s per input (B*S*DM/4)
    for (int i = blockIdx.x * blockDim.x + threadIdx.x; i < 3 * n4; i += gridDim.x * blockDim.x) {
        const int z = i >> 20, off = (i & (n4 - 1)) * 4;
        const float* src = z == 0 ? q : (z == 1 ? k : v);
        unsigned short* dst = z == 0 ? oq : (z == 1 ? ok : ov);
        const float4 f = *reinterpret_cast<const float4*>(&src[off]);
        uint2 p;
        p.x = (unsigned)f2bf(f.x) | ((unsigned)f2bf(f.y) << 16);
        p.y = (unsigned)f2bf(f.z) | ((unsigned)f2bf(f.w) << 16);
        *reinterpret_cast<uint2*>(&dst[off]) = p;
    }
}

// ---------------- weight transpose: Wt[n][k] = bf16(W[k][n]) ----------------
__global__ void transpose_w4(const float* __restrict__ Wq, const float* __restrict__ Wk,
                             const float* __restrict__ Wv, const float* __restrict__ Wo,
                             unsigned short* __restrict__ WtQ, unsigned short* __restrict__ WtK,
                             unsigned short* __restrict__ WtV, unsigned short* __restrict__ WtO) {
    const int z = blockIdx.z;
    const float* W = z == 0 ? Wq : (z == 1 ? Wk : (z == 2 ? Wv : Wo));
    unsigned short* Wt = z == 0 ? WtQ : (z == 1 ? WtK : (z == 2 ? WtV : WtO));
    __shared__ unsigned short t[32][33];
    int tx = threadIdx.x, ty = threadIdx.y; // block (32,8)
    int n0 = blockIdx.x * 32, k0 = blockIdx.y * 32;
#pragma unroll
    for (int i = 0; i < 4; i++) {
        int k = k0 + ty + i * 8;
        t[tx][ty + i * 8] = f2bf(W[k * DM + n0 + tx]);
    }
    __syncthreads();
#pragma unroll
    for (int i = 0; i < 4; i++) {
        int n = n0 + ty + i * 8;
        Wt[n * DM + k0 + tx] = t[ty + i * 8][tx];
    }
}

// ---------------- fused QKV projection, m97-style 128x128 tile ----------------
// C[m][n] = sum_k Xbf[m][k] * Wt[n][k] + bias[n]
// z==0: Q*0.125 -> [B,H,S,64]; z==1: K -> [B,H,S,64]; z==2: V -> [B,H,64,S]
__global__ __launch_bounds__(256) void proj_qkv2(
    const unsigned short* __restrict__ Xq, const unsigned short* __restrict__ Xk,
    const unsigned short* __restrict__ Xv,
    const unsigned short* __restrict__ WtQ, const unsigned short* __restrict__ WtK,
    const unsigned short* __restrict__ WtV,
    const float* __restrict__ bq, const float* __restrict__ bk, const float* __restrict__ bv,
    unsigned short* __restrict__ Qh, unsigned short* __restrict__ Kh, unsigned short* __restrict__ Vt)
{
    const int z = blockIdx.z;
    const unsigned short* X  = z == 0 ? Xq : (z == 1 ? Xk : Xv);
    const unsigned short* Wt = z == 0 ? WtQ : (z == 1 ? WtK : WtV);
    const float* bias = z == 0 ? bq : (z == 1 ? bk : bv);
    unsigned short* out = z == 0 ? Qh : (z == 1 ? Kh : Vt);

    __shared__ __align__(16) unsigned short As[128 * 64];
    __shared__ __align__(16) unsigned short Bs[128 * 64];

    const int tid = threadIdx.x;
    const int w = tid >> 6, lane = tid & 63;
    const int lg = lane >> 4, lr = lane & 15;
    const int wr = w >> 1, wc = w & 1;
    const int m0 = blockIdx.x * 128, n0 = blockIdx.y * 128;

    floatx4 acc[4][4] = {};

    // staging geometry: slot idx = i*256 + tid; row = idx>>3, slot = idx&7
    int srow[4], scol[4], ldsoff[4];
#pragma unroll
    for (int i = 0; i < 4; i++) {
        const int idx = i * 256 + tid;
        srow[i] = idx >> 3;
        scol[i] = ((idx & 7) ^ (srow[i] & 7)) * 8;   // inverse-swizzled source col
        ldsoff[i] = (i * 256 + w * 64) * 8;          // wave-uniform, u16 units
    }

    for (int k0 = 0; k0 < DM; k0 += 64) {
        __syncthreads();
#pragma unroll
        for (int i = 0; i < 4; i++)
            gload16(&X[(size_t)(m0 + srow[i]) * DM + k0 + scol[i]], &As[ldsoff[i]]);
#pragma unroll
        for (int i = 0; i < 4; i++)
            gload16(&Wt[(size_t)(n0 + srow[i]) * DM + k0 + scol[i]], &Bs[ldsoff[i]]);
        __syncthreads();
#pragma unroll
        for (int kk = 0; kk < 2; kk++) {
            short8 a[4], b[4];
#pragma unroll
            for (int mi = 0; mi < 4; mi++) {
                const int r = wr * 64 + mi * 16 + lr;
                a[mi] = *reinterpret_cast<const short8*>(&As[r * 64 + (((kk * 4 + lg) ^ (r & 7)) * 8)]);
            }
#pragma unroll
            for (int ni = 0; ni < 4; ni++) {
                const int r = wc * 64 + ni * 16 + lr;
                b[ni] = *reinterpret_cast<const short8*>(&Bs[r * 64 + (((kk * 4 + lg) ^ (r & 7)) * 8)]);
            }
#pragma unroll
            for (int mi = 0; mi < 4; mi++)
#pragma unroll
                for (int ni = 0; ni < 4; ni++)
                    acc[mi][ni] = mfma16(a[mi], b[ni], acc[mi][ni]);
        }
    }

    const float qscale = (z == 0) ? 0.125f : 1.0f;
#pragma unroll
    for (int mi = 0; mi < 4; mi++)
#pragma unroll
        for (int ni = 0; ni < 4; ni++)
#pragma unroll
            for (int r = 0; r < 4; r++) {
                const int m = m0 + wr * 64 + mi * 16 + lg * 4 + r;
                const int n = n0 + wc * 64 + ni * 16 + lr;
                const float val = (acc[mi][ni][r] + bias[n]) * qscale;
                const int bb = m >> 11, s = m & 2047;
                const int h = n >> 6, d = n & 63;
                const unsigned short o = f2bf(val);
                if (z != 2)
                    out[(((size_t)(bb * NH + h) * SQL) + s) * DKK + d] = o;
                else
                    out[(((size_t)(bb * NH + h) * DKK) + d) * SKL + s] = o;
            }
}

// ---------------- causal flash attention ----------------
// QBLK=64 (2 waves x 32 q rows), KVB=64 double-buffered LDS, 1 barrier/tile,
// next-tile global loads issued post-barrier (latency hidden under compute).
#define KVB 64

__device__ __forceinline__ void load_tile2(uint4* kr, uint4* vr,
    const unsigned short* __restrict__ Kb, const unsigned short* __restrict__ Vb,
    int kv0, int tid)
{
#pragma unroll
    for (int it = 0; it < 4; ++it) {
        const int s = it * 128 + tid;
        const int row = s >> 3, sl = s & 7;
        kr[it] = *reinterpret_cast<const uint4*>(&Kb[(size_t)(kv0 + row) * DKK + sl * 8]);
        vr[it] = *reinterpret_cast<const uint4*>(&Vb[(size_t)row * SKL + kv0 + sl * 8]);
    }
}

__device__ __forceinline__ void store_tile2(unsigned short* kl, unsigned short* vl,
                                            const uint4* kr, const uint4* vr, int tid)
{
#pragma unroll
    for (int it = 0; it < 4; ++it) {
        const int s = it * 128 + tid;
        const int row = s >> 3, sl = s & 7;
        const int off = row * 64 + ((sl ^ (row & 7)) * 8);
        *reinterpret_cast<uint4*>(&kl[off]) = kr[it];
        *reinterpret_cast<uint4*>(&vl[off]) = vr[it];
    }
}

__global__ __launch_bounds__(128) void attn_fwd(
    const unsigned short* __restrict__ Qh, const unsigned short* __restrict__ Kh,
    const unsigned short* __restrict__ Vt, unsigned short* __restrict__ attn)
{
    __shared__ __align__(16) unsigned short Kl[2][4096];
    __shared__ __align__(16) unsigned short Vl[2][4096];
    __shared__ __align__(16) unsigned short Pl[2][2048];

    const int tid = threadIdx.x;
    const int w = tid >> 6, lane = tid & 63;
    const int lg = lane >> 4, lr = lane & 15;
    const int b = blockIdx.z, h = blockIdx.y;
    const int q0 = (int)(gridDim.x - 1 - blockIdx.x) * 64;  // big blocks first
    const int wq0 = q0 + w * 32;

    const unsigned short* Qb = Qh + (size_t)(b * NH + h) * SQL * DKK;
    const unsigned short* Kb = Kh + (size_t)(b * NH + h) * SKL * DKK;
    const unsigned short* Vb = Vt + (size_t)(b * NH + h) * DKK * SKL;

    short8 qf[2][2];
#pragma unroll
    for (int mi = 0; mi < 2; mi++)
#pragma unroll
        for (int kk = 0; kk < 2; kk++)
            qf[mi][kk] = *reinterpret_cast<const short8*>(
                &Qb[(size_t)(wq0 + mi * 16 + lr) * DKK + kk * 32 + lg * 8]);

    floatx4 oa[4][2] = {};                 // O^T accs: [dfrag f][qfrag mi]
    float m_s[2] = {-1e30f, -1e30f};
    float l_s[2] = {0.f, 0.f};

    const int nt = (q0 >> 6) + 1;          // last tile kv0 = q0

    uint4 kr[4], vr[4];
    load_tile2(kr, vr, Kb, Vb, 0, tid);

    for (int t = 0; t < nt; ++t) {
        const int kv0 = t << 6;
        const int cur = t & 1;
        store_tile2(Kl[cur], Vl[cur], kr, vr, tid);
        __syncthreads();                    // the only barrier per tile
        if (t + 1 < nt) load_tile2(kr, vr, Kb, Vb, kv0 + KVB, tid);

        if (kv0 < wq0 + 32) {
            // ---- S^T = K · Q : rows kv (lg*4+r), cols q (lr) ----
            floatx4 sa[4][2] = {};
            __builtin_amdgcn_s_setprio(1);
#pragma unroll
            for (int c = 0; c < 4; c++) {
                const int row = c * 16 + lr;
#pragma unroll
                for (int kk = 0; kk < 2; kk++) {
                    short8 kf = *reinterpret_cast<const short8*>(
                        &Kl[cur][row * 64 + (((kk * 4 + lg) ^ (lr & 7)) * 8)]);
#pragma unroll
                    for (int mi = 0; mi < 2; mi++)
                        sa[c][mi] = mfma16(kf, qf[mi][kk], sa[c][mi]);
                }
            }
            __builtin_amdgcn_s_setprio(0);
            const bool do_mask = (kv0 + KVB - 1 > wq0);
#pragma unroll
            for (int mi = 0; mi < 2; mi++) {
                const int q = wq0 + mi * 16 + lr;
                float pm = -1e30f;
#pragma unroll
                for (int c = 0; c < 4; c++)
#pragma unroll
                    for (int r = 0; r < 4; r++) {
                        float v = sa[c][mi][r];
                        if (do_mask && (kv0 + c * 16 + lg * 4 + r > q)) v = -1e30f;
                        sa[c][mi][r] = v;
                        pm = fmaxf(pm, v);
                    }
                pm = fmaxf(pm, __shfl_xor(pm, 16));
                pm = fmaxf(pm, __shfl_xor(pm, 32));
                const float mn = fmaxf(m_s[mi], pm);
                const float es = __expf(m_s[mi] - mn);
                m_s[mi] = mn;
                float ps = 0.f;
#pragma unroll
                for (int c = 0; c < 4; c++)
#pragma unroll
                    for (int r = 0; r < 4; r++) {
                        float p = __expf(sa[c][mi][r] - mn);
                        sa[c][mi][r] = p;
                        ps += p;
                    }
                ps += __shfl_xor(ps, 16);
                ps += __shfl_xor(ps, 32);
                l_s[mi] = l_s[mi] * es + ps;
#pragma unroll
                for (int f = 0; f < 4; f++)
#pragma unroll
                    for (int r = 0; r < 4; r++)
                        oa[f][mi][r] *= es;
                const int prow = mi * 16 + lr;
#pragma unroll
                for (int c = 0; c < 4; c++) {
                    uint2 pk;
                    pk.x = (unsigned)f2bf(sa[c][mi][0]) | ((unsigned)f2bf(sa[c][mi][1]) << 16);
                    pk.y = (unsigned)f2bf(sa[c][mi][2]) | ((unsigned)f2bf(sa[c][mi][3]) << 16);
                    *reinterpret_cast<uint2*>(
                        &Pl[w][prow * 64 + (((c * 2 + (lg >> 1)) ^ (lr & 7)) * 8) + (lg & 1) * 4]) = pk;
                }
            }
            // ---- O^T += V^T · P^T ----
            short8 pf[2][2];
#pragma unroll
            for (int mi = 0; mi < 2; mi++)
#pragma unroll
                for (int kk = 0; kk < 2; kk++)
                    pf[mi][kk] = *reinterpret_cast<const short8*>(
                        &Pl[w][(mi * 16 + lr) * 64 + (((kk * 4 + lg) ^ (lr & 7)) * 8)]);
            __builtin_amdgcn_s_setprio(1);
#pragma unroll
            for (int f = 0; f < 4; f++) {
                const int row = f * 16 + lr;
#pragma unroll
                for (int kk = 0; kk < 2; kk++) {
                    short8 vt = *reinterpret_cast<const short8*>(
                        &Vl[cur][row * 64 + (((kk * 4 + lg) ^ (lr & 7)) * 8)]);
#pragma unroll
                    for (int mi = 0; mi < 2; mi++)
                        oa[f][mi] = mfma16(vt, pf[mi][kk], oa[f][mi]);
                }
            }
            __builtin_amdgcn_s_setprio(0);
        }
    }

#pragma unroll
    for (int mi = 0; mi < 2; mi++) {
        const float inv = 1.f / l_s[mi];
        const int q = wq0 + mi * 16 + lr;
        unsigned short* dst = &attn[((size_t)(b * SQL + q)) * DM + h * DKK];
#pragma unroll
        for (int f = 0; f < 4; f++) {
            uint2 pk;
            pk.x = (unsigned)f2bf(oa[f][mi][0] * inv) | ((unsigned)f2bf(oa[f][mi][1] * inv) << 16);
            pk.y = (unsigned)f2bf(oa[f][mi][2] * inv) | ((unsigned)f2bf(oa[f][mi][3] * inv) << 16);
            *reinterpret_cast<uint2*>(&dst[f * 16 + lg * 4]) = pk;
        }
    }
}

// ---------------- output projection, 128x64 tile: out = Attn @ Wo + bo (fp32) ----------------
__global__ __launch_bounds__(256) void proj_o2(
    const unsigned short* __restrict__ Attn, const unsigned short* __restrict__ WtO,
    const float* __restrict__ bo, float* __restrict__ out)
{
    __shared__ __align__(16) unsigned short As[128 * 64];
    __shared__ __align__(16) unsigned short Bs[64 * 64];

    const int tid = threadIdx.x;
    const int w = tid >> 6, lane = tid & 63;
    const int lg = lane >> 4, lr = lane & 15;
    const int wr = w >> 1, wc = w & 1;
    const int m0 = blockIdx.x * 128, n0 = blockIdx.y * 64;

    floatx4 acc[4][2] = {};

    int srow[4], scol[4], ldsoff[4];
#pragma unroll
    for (int i = 0; i < 4; i++) {
        const int idx = i * 256 + tid;
        srow[i] = idx >> 3;
        scol[i] = ((idx & 7) ^ (srow[i] & 7)) * 8;
        ldsoff[i] = (i * 256 + w * 64) * 8;
    }

    for (int k0 = 0; k0 < DM; k0 += 64) {
        __syncthreads();
#pragma unroll
        for (int i = 0; i < 4; i++)
            gload16(&Attn[(size_t)(m0 + srow[i]) * DM + k0 + scol[i]], &As[ldsoff[i]]);
#pragma unroll
        for (int i = 0; i < 2; i++)
            gload16(&WtO[(size_t)(n0 + srow[i]) * DM + k0 + scol[i]], &Bs[ldsoff[i]]);
        __syncthreads();
#pragma unroll
        for (int kk = 0; kk < 2; kk++) {
            short8 a[4], b[2];
#pragma unroll
            for (int mi = 0; mi < 4; mi++) {
                const int r = wr * 64 + mi * 16 + lr;
                a[mi] = *reinterpret_cast<const short8*>(&As[r * 64 + (((kk * 4 + lg) ^ (r & 7)) * 8)]);
            }
#pragma unroll
            for (int ni = 0; ni < 2; ni++) {
                const int r = wc * 32 + ni * 16 + lr;
                b[ni] = *reinterpret_cast<const short8*>(&Bs[r * 64 + (((kk * 4 + lg) ^ (r & 7)) * 8)]);
            }
#pragma unroll
            for (int mi = 0; mi < 4; mi++)
#pragma unroll
                for (int ni = 0; ni < 2; ni++)
                    acc[mi][ni] = mfma16(a[mi], b[ni], acc[mi][ni]);
        }
    }

#pragma unroll
    for (int mi = 0; mi < 4; mi++)
#pragma unroll
        for (int ni = 0; ni < 2; ni++)
#pragma unroll
            for (int r = 0; r < 4; r++) {
                const int m = m0 + wr * 64 + mi * 16 + lg * 4 + r;
                const int n = n0 + wc * 32 + ni * 16 + lr;
                out[(size_t)m * DM + n] = acc[mi][ni][r] + bo[n];
            }
}

extern "C" void kernel_launch(void* const* d_in, const int* in_sizes, int n_in,
                              void* d_out, int out_size, void* d_ws, size_t ws_size,
                              hipStream_t stream) {
    const float* query = (const float*)d_in[0];
    const float* key   = (const float*)d_in[1];
    const float* value = (const float*)d_in[2];
    const float* Wq = (const float*)d_in[4];
    const float* bq = (const float*)d_in[5];
    const float* Wk = (const float*)d_in[6];
    const float* bk = (const float*)d_in[7];
    const float* Wv = (const float*)d_in[8];
    const float* bv = (const float*)d_in[9];
    const float* Wo = (const float*)d_in[10];
    const float* bo = (const float*)d_in[11];
    float* out = (float*)d_out;

    unsigned short* ws = (unsigned short*)d_ws;
    const size_t MW = (size_t)DM * DM;            // 1M elems
    const size_t MH = (size_t)NB * NH * SQL * DKK; // 4.19M elems
    unsigned short* WtQ = ws;
    unsigned short* WtK = WtQ + MW;
    unsigned short* WtV = WtK + MW;
    unsigned short* WtO = WtV + MW;
    unsigned short* Qh  = WtO + MW;
    unsigned short* Kh  = Qh + MH;
    unsigned short* Vt  = Kh + MH;
    unsigned short* At  = Vt + MH;
    // scratch aliases (liveness-checked):
    //   Xbf_q, Xbf_k live in d_out (dead before proj_o2 writes out)
    //   Xbf_v aliases At (dead until attn_fwd writes At)
    unsigned short* Xbq = (unsigned short*)d_out;
    unsigned short* Xbk = Xbq + MH;
    unsigned short* Xbv = At;

    x2bf<<<2048, 256, 0, stream>>>(query, key, value, Xbq, Xbk, Xbv);
    transpose_w4<<<dim3(32, 32, 4), dim3(32, 8), 0, stream>>>(Wq, Wk, Wv, Wo, WtQ, WtK, WtV, WtO);
    proj_qkv2<<<dim3(32, 8, 3), 256, 0, stream>>>(Xbq, Xbk, Xbv, WtQ, WtK, WtV,
                                                  bq, bk, bv, Qh, Kh, Vt);
    attn_fwd<<<dim3(SQL / 64, NH, NB), 128, 0, stream>>>(Qh, Kh, Vt, At);
    proj_o2<<<dim3(32, 16), 256, 0, stream>>>(At, WtO, bo, out);
}

// Round 5
// 310.262 us; speedup vs baseline: 1.1496x; 1.1496x over previous
//
#include <hip/hip_runtime.h>
#include <hip/hip_bf16.h>

#define DM 1024
#define NH 16
#define DKK 64
#define NB 2
#define SQL 2048
#define SKL 2048

typedef __attribute__((ext_vector_type(8))) short short8;
typedef __attribute__((ext_vector_type(4))) float floatx4;

static __device__ inline floatx4 mfma16(short8 a, short8 b, floatx4 c) {
    return __builtin_amdgcn_mfma_f32_16x16x32_bf16(a, b, c, 0, 0, 0);
}

// native convert: compiler fuses pairs into v_cvt_pk_bf16_f32 (m240)
static __device__ inline unsigned short f2bf(float f) {
    __hip_bfloat16 h = __float2bfloat16(f);
    return *reinterpret_cast<unsigned short*>(&h);
}

// async global(16B/lane) -> LDS (linear, wave-uniform base + lane*16)
__device__ __forceinline__ void gload16(const void* g, void* l) {
    __builtin_amdgcn_global_load_lds(
        (const __attribute__((address_space(1))) void*)g,
        (__attribute__((address_space(3))) void*)l, 16, 0, 0);
}

// ---------------- fp32 -> bf16 conversion of Q/K/V inputs ----------------
__global__ __launch_bounds__(256) void x2bf(
    const float* __restrict__ q, const float* __restrict__ k, const float* __restrict__ v,
    unsigned short* __restrict__ oq, unsigned short* __restrict__ ok, unsigned short* __restrict__ ov)
{
    const int n4 = 1 << 20;  // float4s per input (B*S*DM/4)
    for (int i = blockIdx.x * blockDim.x + threadIdx.x; i < 3 * n4; i += gridDim.x * blockDim.x) {
        const int z = i >> 20, off = (i & (n4 - 1)) * 4;
        const float* src = z == 0 ? q : (z == 1 ? k : v);
        unsigned short* dst = z == 0 ? oq : (z == 1 ? ok : ov);
        const float4 f = *reinterpret_cast<const float4*>(&src[off]);
        uint2 p;
        p.x = (unsigned)f2bf(f.x) | ((unsigned)f2bf(f.y) << 16);
        p.y = (unsigned)f2bf(f.z) | ((unsigned)f2bf(f.w) << 16);
        *reinterpret_cast<uint2*>(&dst[off]) = p;
    }
}

// ---------------- weight transpose: Wt[n][k] = bf16(W[k][n]) ----------------
__global__ void transpose_w4(const float* __restrict__ Wq, const float* __restrict__ Wk,
                             const float* __restrict__ Wv, const float* __restrict__ Wo,
                             unsigned short* __restrict__ WtQ, unsigned short* __restrict__ WtK,
                             unsigned short* __restrict__ WtV, unsigned short* __restrict__ WtO) {
    const int z = blockIdx.z;
    const float* W = z == 0 ? Wq : (z == 1 ? Wk : (z == 2 ? Wv : Wo));
    unsigned short* Wt = z == 0 ? WtQ : (z == 1 ? WtK : (z == 2 ? WtV : WtO));
    __shared__ unsigned short t[32][33];
    int tx = threadIdx.x, ty = threadIdx.y; // block (32,8)
    int n0 = blockIdx.x * 32, k0 = blockIdx.y * 32;
#pragma unroll
    for (int i = 0; i < 4; i++) {
        int k = k0 + ty + i * 8;
        t[tx][ty + i * 8] = f2bf(W[k * DM + n0 + tx]);
    }
    __syncthreads();
#pragma unroll
    for (int i = 0; i < 4; i++) {
        int n = n0 + ty + i * 8;
        Wt[n * DM + k0 + tx] = t[ty + i * 8][tx];
    }
}

// ---------------- fused QKV projection, m97-style 128x128 tile ----------------
// C[m][n] = sum_k Xbf[m][k] * Wt[n][k] + bias[n]
// z==0: Q*0.125 -> [B,H,S,64]; z==1: K -> [B,H,S,64]; z==2: V -> [B,H,64,S]
__global__ __launch_bounds__(256) void proj_qkv2(
    const unsigned short* __restrict__ Xq, const unsigned short* __restrict__ Xk,
    const unsigned short* __restrict__ Xv,
    const unsigned short* __restrict__ WtQ, const unsigned short* __restrict__ WtK,
    const unsigned short* __restrict__ WtV,
    const float* __restrict__ bq, const float* __restrict__ bk, const float* __restrict__ bv,
    unsigned short* __restrict__ Qh, unsigned short* __restrict__ Kh, unsigned short* __restrict__ Vt)
{
    const int z = blockIdx.z;
    const unsigned short* X  = z == 0 ? Xq : (z == 1 ? Xk : Xv);
    const unsigned short* Wt = z == 0 ? WtQ : (z == 1 ? WtK : WtV);
    const float* bias = z == 0 ? bq : (z == 1 ? bk : bv);
    unsigned short* out = z == 0 ? Qh : (z == 1 ? Kh : Vt);

    __shared__ __align__(16) unsigned short As[128 * 64];
    __shared__ __align__(16) unsigned short Bs[128 * 64];

    const int tid = threadIdx.x;
    const int w = tid >> 6, lane = tid & 63;
    const int lg = lane >> 4, lr = lane & 15;
    const int wr = w >> 1, wc = w & 1;
    const int m0 = blockIdx.x * 128, n0 = blockIdx.y * 128;

    floatx4 acc[4][4] = {};

    int srow[4], scol[4], ldsoff[4];
#pragma unroll
    for (int i = 0; i < 4; i++) {
        const int idx = i * 256 + tid;
        srow[i] = idx >> 3;
        scol[i] = ((idx & 7) ^ (srow[i] & 7)) * 8;   // inverse-swizzled source col
        ldsoff[i] = (i * 256 + w * 64) * 8;          // wave-uniform, u16 units
    }

    for (int k0 = 0; k0 < DM; k0 += 64) {
        __syncthreads();
#pragma unroll
        for (int i = 0; i < 4; i++)
            gload16(&X[(size_t)(m0 + srow[i]) * DM + k0 + scol[i]], &As[ldsoff[i]]);
#pragma unroll
        for (int i = 0; i < 4; i++)
            gload16(&Wt[(size_t)(n0 + srow[i]) * DM + k0 + scol[i]], &Bs[ldsoff[i]]);
        __syncthreads();
#pragma unroll
        for (int kk = 0; kk < 2; kk++) {
            short8 a[4], b[4];
#pragma unroll
            for (int mi = 0; mi < 4; mi++) {
                const int r = wr * 64 + mi * 16 + lr;
                a[mi] = *reinterpret_cast<const short8*>(&As[r * 64 + (((kk * 4 + lg) ^ (r & 7)) * 8)]);
            }
#pragma unroll
            for (int ni = 0; ni < 4; ni++) {
                const int r = wc * 64 + ni * 16 + lr;
                b[ni] = *reinterpret_cast<const short8*>(&Bs[r * 64 + (((kk * 4 + lg) ^ (r & 7)) * 8)]);
            }
#pragma unroll
            for (int mi = 0; mi < 4; mi++)
#pragma unroll
                for (int ni = 0; ni < 4; ni++)
                    acc[mi][ni] = mfma16(a[mi], b[ni], acc[mi][ni]);
        }
    }

    const float qscale = (z == 0) ? 0.125f : 1.0f;
#pragma unroll
    for (int mi = 0; mi < 4; mi++)
#pragma unroll
        for (int ni = 0; ni < 4; ni++)
#pragma unroll
            for (int r = 0; r < 4; r++) {
                const int m = m0 + wr * 64 + mi * 16 + lg * 4 + r;
                const int n = n0 + wc * 64 + ni * 16 + lr;
                const float val = (acc[mi][ni][r] + bias[n]) * qscale;
                const int bb = m >> 11, s = m & 2047;
                const int h = n >> 6, d = n & 63;
                const unsigned short o = f2bf(val);
                if (z != 2)
                    out[(((size_t)(bb * NH + h) * SQL) + s) * DKK + d] = o;
                else
                    out[(((size_t)(bb * NH + h) * DKK) + d) * SKL + s] = o;
            }
}

// ---------------- causal flash attention ----------------
// QBLK=128 (4 waves x 32 q rows), KVB=64 double-buffered LDS.
// Per tile: store; sync; issue-loads(t+1); compute; sync  (loads fly under compute)
#define KVB 64

__device__ __forceinline__ void load_tile(uint4* kr, uint4* vr,
    const unsigned short* __restrict__ Kb, const unsigned short* __restrict__ Vb,
    int kv0, int tid)
{
#pragma unroll
    for (int it = 0; it < 2; ++it) {
        const int s = it * 256 + tid;
        const int row = s >> 3, sl = s & 7;
        kr[it] = *reinterpret_cast<const uint4*>(&Kb[(size_t)(kv0 + row) * DKK + sl * 8]);
        vr[it] = *reinterpret_cast<const uint4*>(&Vb[(size_t)row * SKL + kv0 + sl * 8]);
    }
}

__device__ __forceinline__ void store_tile(unsigned short* kl, unsigned short* vl,
                                           const uint4* kr, const uint4* vr, int tid)
{
#pragma unroll
    for (int it = 0; it < 2; ++it) {
        const int s = it * 256 + tid;
        const int row = s >> 3, sl = s & 7;
        const int off = row * 64 + ((sl ^ (row & 7)) * 8);
        *reinterpret_cast<uint4*>(&kl[off]) = kr[it];
        *reinterpret_cast<uint4*>(&vl[off]) = vr[it];
    }
}

__global__ __launch_bounds__(256) void attn_fwd(
    const unsigned short* __restrict__ Qh, const unsigned short* __restrict__ Kh,
    const unsigned short* __restrict__ Vt, unsigned short* __restrict__ attn)
{
    __shared__ __align__(16) unsigned short Kl[2][4096];
    __shared__ __align__(16) unsigned short Vl[2][4096];
    __shared__ __align__(16) unsigned short Pl[4][2048];

    const int tid = threadIdx.x;
    const int w = tid >> 6, lane = tid & 63;
    const int lg = lane >> 4, lr = lane & 15;
    const int b = blockIdx.z, h = blockIdx.y;
    const int q0 = (int)(gridDim.x - 1 - blockIdx.x) * 128;  // big blocks first
    const int wq0 = q0 + w * 32;

    const unsigned short* Qb = Qh + (size_t)(b * NH + h) * SQL * DKK;
    const unsigned short* Kb = Kh + (size_t)(b * NH + h) * SKL * DKK;
    const unsigned short* Vb = Vt + (size_t)(b * NH + h) * DKK * SKL;

    short8 qf[2][2];
#pragma unroll
    for (int mi = 0; mi < 2; mi++)
#pragma unroll
        for (int kk = 0; kk < 2; kk++)
            qf[mi][kk] = *reinterpret_cast<const short8*>(
                &Qb[(size_t)(wq0 + mi * 16 + lr) * DKK + kk * 32 + lg * 8]);

    floatx4 oa[4][2] = {};                 // O^T accs: [dfrag f][qfrag mi]
    float m_s[2] = {-1e30f, -1e30f};
    float l_s[2] = {0.f, 0.f};

    const int nt = (q0 >> 6) + 2;

    uint4 kr[2], vr[2];
    load_tile(kr, vr, Kb, Vb, 0, tid);

    for (int t = 0; t < nt; ++t) {
        const int kv0 = t << 6;
        const int cur = t & 1;
        store_tile(Kl[cur], Vl[cur], kr, vr, tid);
        __syncthreads();
        if (t + 1 < nt) load_tile(kr, vr, Kb, Vb, kv0 + KVB, tid);  // fly under compute

        if (kv0 < wq0 + 32) {
            // ---- S^T = K · Q : rows kv (lg*4+r), cols q (lr) ----
            floatx4 sa[4][2] = {};
            __builtin_amdgcn_s_setprio(1);
#pragma unroll
            for (int c = 0; c < 4; c++) {
                const int row = c * 16 + lr;
#pragma unroll
                for (int kk = 0; kk < 2; kk++) {
                    short8 kf = *reinterpret_cast<const short8*>(
                        &Kl[cur][row * 64 + (((kk * 4 + lg) ^ (lr & 7)) * 8)]);
#pragma unroll
                    for (int mi = 0; mi < 2; mi++)
                        sa[c][mi] = mfma16(kf, qf[mi][kk], sa[c][mi]);
                }
            }
            __builtin_amdgcn_s_setprio(0);
            const bool do_mask = (kv0 + KVB - 1 > wq0);
#pragma unroll
            for (int mi = 0; mi < 2; mi++) {
                const int q = wq0 + mi * 16 + lr;
                float pm = -1e30f;
#pragma unroll
                for (int c = 0; c < 4; c++)
#pragma unroll
                    for (int r = 0; r < 4; r++) {
                        float v = sa[c][mi][r];
                        if (do_mask && (kv0 + c * 16 + lg * 4 + r > q)) v = -1e30f;
                        sa[c][mi][r] = v;
                        pm = fmaxf(pm, v);
                    }
                pm = fmaxf(pm, __shfl_xor(pm, 16));
                pm = fmaxf(pm, __shfl_xor(pm, 32));
                const float mn = fmaxf(m_s[mi], pm);
                const float es = __expf(m_s[mi] - mn);
                m_s[mi] = mn;
                float ps = 0.f;
#pragma unroll
                for (int c = 0; c < 4; c++)
#pragma unroll
                    for (int r = 0; r < 4; r++) {
                        float p = __expf(sa[c][mi][r] - mn);
                        sa[c][mi][r] = p;
                        ps += p;
                    }
                ps += __shfl_xor(ps, 16);
                ps += __shfl_xor(ps, 32);
                l_s[mi] = l_s[mi] * es + ps;
#pragma unroll
                for (int f = 0; f < 4; f++)
#pragma unroll
                    for (int r = 0; r < 4; r++)
                        oa[f][mi][r] *= es;
                const int prow = mi * 16 + lr;
#pragma unroll
                for (int c = 0; c < 4; c++) {
                    uint2 pk;
                    pk.x = (unsigned)f2bf(sa[c][mi][0]) | ((unsigned)f2bf(sa[c][mi][1]) << 16);
                    pk.y = (unsigned)f2bf(sa[c][mi][2]) | ((unsigned)f2bf(sa[c][mi][3]) << 16);
                    *reinterpret_cast<uint2*>(
                        &Pl[w][prow * 64 + (((c * 2 + (lg >> 1)) ^ (lr & 7)) * 8) + (lg & 1) * 4]) = pk;
                }
            }
            // ---- O^T += V^T · P^T ----
            short8 pf[2][2];
#pragma unroll
            for (int mi = 0; mi < 2; mi++)
#pragma unroll
                for (int kk = 0; kk < 2; kk++)
                    pf[mi][kk] = *reinterpret_cast<const short8*>(
                        &Pl[w][(mi * 16 + lr) * 64 + (((kk * 4 + lg) ^ (lr & 7)) * 8)]);
            __builtin_amdgcn_s_setprio(1);
#pragma unroll
            for (int f = 0; f < 4; f++) {
                const int row = f * 16 + lr;
#pragma unroll
                for (int kk = 0; kk < 2; kk++) {
                    short8 vt = *reinterpret_cast<const short8*>(
                        &Vl[cur][row * 64 + (((kk * 4 + lg) ^ (lr & 7)) * 8)]);
#pragma unroll
                    for (int mi = 0; mi < 2; mi++)
                        oa[f][mi] = mfma16(vt, pf[mi][kk], oa[f][mi]);
                }
            }
            __builtin_amdgcn_s_setprio(0);
        }
        __syncthreads();
    }

    // ---- coalesced O epilogue: stage O^T into Pl[w] (swizzled), read back rows ----
#pragma unroll
    for (int mi = 0; mi < 2; mi++) {
        const float inv = 1.f / l_s[mi];
        const int prow = mi * 16 + lr;         // q-local row
#pragma unroll
        for (int f = 0; f < 4; f++) {
            uint2 pk;
            pk.x = (unsigned)f2bf(oa[f][mi][0] * inv) | ((unsigned)f2bf(oa[f][mi][1] * inv) << 16);
            pk.y = (unsigned)f2bf(oa[f][mi][2] * inv) | ((unsigned)f2bf(oa[f][mi][3] * inv) << 16);
            // d = f*16 + lg*4 + {0..3}; 16B slot = (f*2 + (lg>>1)) ^ (prow&7); half = lg&1
            *reinterpret_cast<uint2*>(
                &Pl[w][prow * 64 + (((f * 2 + (lg >> 1)) ^ (prow & 7)) * 8) + (lg & 1) * 4]) = pk;
        }
    }
    // read back: lane covers row rl = i*8 + (lane>>3), slot = lane&7 (deswizzled)
#pragma unroll
    for (int i = 0; i < 4; i++) {
        const int rl = i * 8 + (lane >> 3);
        const int slot = lane & 7;
        const uint4 o = *reinterpret_cast<const uint4*>(
            &Pl[w][rl * 64 + ((slot ^ (rl & 7)) * 8)]);
        const int q = wq0 + rl;
        *reinterpret_cast<uint4*>(
            &attn[((size_t)(b * SQL + q)) * DM + h * DKK + slot * 8]) = o;
    }
}

// ---------------- output projection, 128x64 tile: out = Attn @ Wo + bo (fp32) ----------------
__global__ __launch_bounds__(256) void proj_o2(
    const unsigned short* __restrict__ Attn, const unsigned short* __restrict__ WtO,
    const float* __restrict__ bo, float* __restrict__ out)
{
    __shared__ __align__(16) unsigned short As[128 * 64];
    __shared__ __align__(16) unsigned short Bs[64 * 64];

    const int tid = threadIdx.x;
    const int w = tid >> 6, lane = tid & 63;
    const int lg = lane >> 4, lr = lane & 15;
    const int wr = w >> 1, wc = w & 1;
    const int m0 = blockIdx.x * 128, n0 = blockIdx.y * 64;

    floatx4 acc[4][2] = {};

    int srow[4], scol[4], ldsoff[4];
#pragma unroll
    for (int i = 0; i < 4; i++) {
        const int idx = i * 256 + tid;
        srow[i] = idx >> 3;
        scol[i] = ((idx & 7) ^ (srow[i] & 7)) * 8;
        ldsoff[i] = (i * 256 + w * 64) * 8;
    }

    for (int k0 = 0; k0 < DM; k0 += 64) {
        __syncthreads();
#pragma unroll
        for (int i = 0; i < 4; i++)
            gload16(&Attn[(size_t)(m0 + srow[i]) * DM + k0 + scol[i]], &As[ldsoff[i]]);
#pragma unroll
        for (int i = 0; i < 2; i++)
            gload16(&WtO[(size_t)(n0 + srow[i]) * DM + k0 + scol[i]], &Bs[ldsoff[i]]);
        __syncthreads();
#pragma unroll
        for (int kk = 0; kk < 2; kk++) {
            short8 a[4], b[2];
#pragma unroll
            for (int mi = 0; mi < 4; mi++) {
                const int r = wr * 64 + mi * 16 + lr;
                a[mi] = *reinterpret_cast<const short8*>(&As[r * 64 + (((kk * 4 + lg) ^ (r & 7)) * 8)]);
            }
#pragma unroll
            for (int ni = 0; ni < 2; ni++) {
                const int r = wc * 32 + ni * 16 + lr;
                b[ni] = *reinterpret_cast<const short8*>(&Bs[r * 64 + (((kk * 4 + lg) ^ (r & 7)) * 8)]);
            }
#pragma unroll
            for (int mi = 0; mi < 4; mi++)
#pragma unroll
                for (int ni = 0; ni < 2; ni++)
                    acc[mi][ni] = mfma16(a[mi], b[ni], acc[mi][ni]);
        }
    }

#pragma unroll
    for (int mi = 0; mi < 4; mi++)
#pragma unroll
        for (int ni = 0; ni < 2; ni++)
#pragma unroll
            for (int r = 0; r < 4; r++) {
                const int m = m0 + wr * 64 + mi * 16 + lg * 4 + r;
                const int n = n0 + wc * 32 + ni * 16 + lr;
                out[(size_t)m * DM + n] = acc[mi][ni][r] + bo[n];
            }
}

extern "C" void kernel_launch(void* const* d_in, const int* in_sizes, int n_in,
                              void* d_out, int out_size, void* d_ws, size_t ws_size,
                              hipStream_t stream) {
    const float* query = (const float*)d_in[0];
    const float* key   = (const float*)d_in[1];
    const float* value = (const float*)d_in[2];
    const float* Wq = (const float*)d_in[4];
    const float* bq = (const float*)d_in[5];
    const float* Wk = (const float*)d_in[6];
    const float* bk = (const float*)d_in[7];
    const float* Wv = (const float*)d_in[8];
    const float* bv = (const float*)d_in[9];
    const float* Wo = (const float*)d_in[10];
    const float* bo = (const float*)d_in[11];
    float* out = (float*)d_out;

    unsigned short* ws = (unsigned short*)d_ws;
    const size_t MW = (size_t)DM * DM;            // 1M elems
    const size_t MH = (size_t)NB * NH * SQL * DKK; // 4.19M elems
    unsigned short* WtQ = ws;
    unsigned short* WtK = WtQ + MW;
    unsigned short* WtV = WtK + MW;
    unsigned short* WtO = WtV + MW;
    unsigned short* Qh  = WtO + MW;
    unsigned short* Kh  = Qh + MH;
    unsigned short* Vt  = Kh + MH;
    unsigned short* At  = Vt + MH;
    // scratch aliases (liveness-checked):
    //   Xbf_q, Xbf_k live in d_out (dead before proj_o2 writes out)
    //   Xbf_v aliases At (dead until attn_fwd writes At)
    unsigned short* Xbq = (unsigned short*)d_out;
    unsigned short* Xbk = Xbq + MH;
    unsigned short* Xbv = At;

    x2bf<<<2048, 256, 0, stream>>>(query, key, value, Xbq, Xbk, Xbv);
    transpose_w4<<<dim3(32, 32, 4), dim3(32, 8), 0, stream>>>(Wq, Wk, Wv, Wo, WtQ, WtK, WtV, WtO);
    proj_qkv2<<<dim3(32, 8, 3), 256, 0, stream>>>(Xbq, Xbk, Xbv, WtQ, WtK, WtV,
                                                  bq, bk, bv, Qh, Kh, Vt);
    attn_fwd<<<dim3(SQL / 128, NH, NB), 256, 0, stream>>>(Qh, Kh, Vt, At);
    proj_o2<<<dim3(32, 16), 256, 0, stream>>>(At, WtO, bo, out);
}

// Round 6
// 277.291 us; speedup vs baseline: 1.2863x; 1.1189x over previous
//
#include <hip/hip_runtime.h>
#include <hip/hip_bf16.h>

#define DM 1024
#define NH 16
#define DKK 64
#define NB 2
#define SQL 2048
#define SKL 2048

typedef __attribute__((ext_vector_type(8))) short short8;
typedef __attribute__((ext_vector_type(4))) float floatx4;

static __device__ inline floatx4 mfma16(short8 a, short8 b, floatx4 c) {
    return __builtin_amdgcn_mfma_f32_16x16x32_bf16(a, b, c, 0, 0, 0);
}

// native convert: compiler fuses pairs into v_cvt_pk_bf16_f32 (m240)
static __device__ inline unsigned short f2bf(float f) {
    __hip_bfloat16 h = __float2bfloat16(f);
    return *reinterpret_cast<unsigned short*>(&h);
}

// async global(16B/lane) -> LDS (linear, wave-uniform base + lane*16)
__device__ __forceinline__ void gload16(const void* g, void* l) {
    __builtin_amdgcn_global_load_lds(
        (const __attribute__((address_space(1))) void*)g,
        (__attribute__((address_space(3))) void*)l, 16, 0, 0);
}

// ---------------- fp32 -> bf16 conversion of Q/K/V inputs ----------------
__global__ __launch_bounds__(256) void x2bf(
    const float* __restrict__ q, const float* __restrict__ k, const float* __restrict__ v,
    unsigned short* __restrict__ oq, unsigned short* __restrict__ ok, unsigned short* __restrict__ ov)
{
    const int n4 = 1 << 20;  // float4s per input (B*S*DM/4)
    for (int i = blockIdx.x * blockDim.x + threadIdx.x; i < 3 * n4; i += gridDim.x * blockDim.x) {
        const int z = i >> 20, off = (i & (n4 - 1)) * 4;
        const float* src = z == 0 ? q : (z == 1 ? k : v);
        unsigned short* dst = z == 0 ? oq : (z == 1 ? ok : ov);
        const float4 f = *reinterpret_cast<const float4*>(&src[off]);
        uint2 p;
        p.x = (unsigned)f2bf(f.x) | ((unsigned)f2bf(f.y) << 16);
        p.y = (unsigned)f2bf(f.z) | ((unsigned)f2bf(f.w) << 16);
        *reinterpret_cast<uint2*>(&dst[off]) = p;
    }
}

// ---------------- weight transpose: Wt[n][k] = bf16(W[k][n]) ----------------
__global__ void transpose_w4(const float* __restrict__ Wq, const float* __restrict__ Wk,
                             const float* __restrict__ Wv, const float* __restrict__ Wo,
                             unsigned short* __restrict__ WtQ, unsigned short* __restrict__ WtK,
                             unsigned short* __restrict__ WtV, unsigned short* __restrict__ WtO) {
    const int z = blockIdx.z;
    const float* W = z == 0 ? Wq : (z == 1 ? Wk : (z == 2 ? Wv : Wo));
    unsigned short* Wt = z == 0 ? WtQ : (z == 1 ? WtK : (z == 2 ? WtV : WtO));
    __shared__ unsigned short t[32][33];
    int tx = threadIdx.x, ty = threadIdx.y; // block (32,8)
    int n0 = blockIdx.x * 32, k0 = blockIdx.y * 32;
#pragma unroll
    for (int i = 0; i < 4; i++) {
        int k = k0 + ty + i * 8;
        t[tx][ty + i * 8] = f2bf(W[k * DM + n0 + tx]);
    }
    __syncthreads();
#pragma unroll
    for (int i = 0; i < 4; i++) {
        int n = n0 + ty + i * 8;
        Wt[n * DM + k0 + tx] = t[ty + i * 8][tx];
    }
}

// ---------------- fused QKV projection, m97-style 128x128 tile ----------------
// C[m][n] = sum_k Xbf[m][k] * Wt[n][k] + bias[n]
// z==0: Q*0.125 -> [B,H,S,64]; z==1: K -> [B,H,S,64]; z==2: V -> [B,H,64,S]
__global__ __launch_bounds__(256) void proj_qkv2(
    const unsigned short* __restrict__ Xq, const unsigned short* __restrict__ Xk,
    const unsigned short* __restrict__ Xv,
    const unsigned short* __restrict__ WtQ, const unsigned short* __restrict__ WtK,
    const unsigned short* __restrict__ WtV,
    const float* __restrict__ bq, const float* __restrict__ bk, const float* __restrict__ bv,
    unsigned short* __restrict__ Qh, unsigned short* __restrict__ Kh, unsigned short* __restrict__ Vt)
{
    const int z = blockIdx.z;
    const unsigned short* X  = z == 0 ? Xq : (z == 1 ? Xk : Xv);
    const unsigned short* Wt = z == 0 ? WtQ : (z == 1 ? WtK : WtV);
    const float* bias = z == 0 ? bq : (z == 1 ? bk : bv);
    unsigned short* out = z == 0 ? Qh : (z == 1 ? Kh : Vt);

    __shared__ __align__(16) unsigned short As[128 * 64];
    __shared__ __align__(16) unsigned short Bs[128 * 64];

    const int tid = threadIdx.x;
    const int w = tid >> 6, lane = tid & 63;
    const int lg = lane >> 4, lr = lane & 15;
    const int wr = w >> 1, wc = w & 1;
    const int m0 = blockIdx.x * 128, n0 = blockIdx.y * 128;

    floatx4 acc[4][4] = {};

    int srow[4], scol[4], ldsoff[4];
#pragma unroll
    for (int i = 0; i < 4; i++) {
        const int idx = i * 256 + tid;
        srow[i] = idx >> 3;
        scol[i] = ((idx & 7) ^ (srow[i] & 7)) * 8;   // inverse-swizzled source col
        ldsoff[i] = (i * 256 + w * 64) * 8;          // wave-uniform, u16 units
    }

    for (int k0 = 0; k0 < DM; k0 += 64) {
        __syncthreads();
#pragma unroll
        for (int i = 0; i < 4; i++)
            gload16(&X[(size_t)(m0 + srow[i]) * DM + k0 + scol[i]], &As[ldsoff[i]]);
#pragma unroll
        for (int i = 0; i < 4; i++)
            gload16(&Wt[(size_t)(n0 + srow[i]) * DM + k0 + scol[i]], &Bs[ldsoff[i]]);
        __syncthreads();
#pragma unroll
        for (int kk = 0; kk < 2; kk++) {
            short8 a[4], b[4];
#pragma unroll
            for (int mi = 0; mi < 4; mi++) {
                const int r = wr * 64 + mi * 16 + lr;
                a[mi] = *reinterpret_cast<const short8*>(&As[r * 64 + (((kk * 4 + lg) ^ (r & 7)) * 8)]);
            }
#pragma unroll
            for (int ni = 0; ni < 4; ni++) {
                const int r = wc * 64 + ni * 16 + lr;
                b[ni] = *reinterpret_cast<const short8*>(&Bs[r * 64 + (((kk * 4 + lg) ^ (r & 7)) * 8)]);
            }
#pragma unroll
            for (int mi = 0; mi < 4; mi++)
#pragma unroll
                for (int ni = 0; ni < 4; ni++)
                    acc[mi][ni] = mfma16(a[mi], b[ni], acc[mi][ni]);
        }
    }

    const float qscale = (z == 0) ? 0.125f : 1.0f;
#pragma unroll
    for (int mi = 0; mi < 4; mi++)
#pragma unroll
        for (int ni = 0; ni < 4; ni++)
#pragma unroll
            for (int r = 0; r < 4; r++) {
                const int m = m0 + wr * 64 + mi * 16 + lg * 4 + r;
                const int n = n0 + wc * 64 + ni * 16 + lr;
                const float val = (acc[mi][ni][r] + bias[n]) * qscale;
                const int bb = m >> 11, s = m & 2047;
                const int h = n >> 6, d = n & 63;
                const unsigned short o = f2bf(val);
                if (z != 2)
                    out[(((size_t)(bb * NH + h) * SQL) + s) * DKK + d] = o;
                else
                    out[(((size_t)(bb * NH + h) * DKK) + d) * SKL + s] = o;
            }
}

// ---------------- causal flash attention ----------------
// QBLK=256 (8 waves x 32 q rows), 512 threads, grid = 256 blocks = 1/CU.
// KVB=64 double-buffered LDS; per tile: store; sync; issue-loads(t+1); compute; sync
#define KVB 64

__device__ __forceinline__ void load_tile(uint4* kr, uint4* vr,
    const unsigned short* __restrict__ Kb, const unsigned short* __restrict__ Vb,
    int kv0, int tid)
{
    const int row = tid >> 3, sl = tid & 7;   // 512 threads: 64 rows x 8 slots
    *kr = *reinterpret_cast<const uint4*>(&Kb[(size_t)(kv0 + row) * DKK + sl * 8]);
    *vr = *reinterpret_cast<const uint4*>(&Vb[(size_t)row * SKL + kv0 + sl * 8]);
}

__device__ __forceinline__ void store_tile(unsigned short* kl, unsigned short* vl,
                                           const uint4* kr, const uint4* vr, int tid)
{
    const int row = tid >> 3, sl = tid & 7;
    const int off = row * 64 + ((sl ^ (row & 7)) * 8);
    *reinterpret_cast<uint4*>(&kl[off]) = *kr;
    *reinterpret_cast<uint4*>(&vl[off]) = *vr;
}

__global__ __launch_bounds__(512) void attn_fwd(
    const unsigned short* __restrict__ Qh, const unsigned short* __restrict__ Kh,
    const unsigned short* __restrict__ Vt, unsigned short* __restrict__ attn)
{
    __shared__ __align__(16) unsigned short Kl[2][4096];
    __shared__ __align__(16) unsigned short Vl[2][4096];
    __shared__ __align__(16) unsigned short Pl[8][2048];

    const int tid = threadIdx.x;
    const int w = tid >> 6, lane = tid & 63;
    const int lg = lane >> 4, lr = lane & 15;
    const int b = blockIdx.z, h = blockIdx.y;
    const int q0 = (int)(gridDim.x - 1 - blockIdx.x) * 256;  // big blocks first
    const int wq0 = q0 + w * 32;

    const unsigned short* Qb = Qh + (size_t)(b * NH + h) * SQL * DKK;
    const unsigned short* Kb = Kh + (size_t)(b * NH + h) * SKL * DKK;
    const unsigned short* Vb = Vt + (size_t)(b * NH + h) * DKK * SKL;

    short8 qf[2][2];
#pragma unroll
    for (int mi = 0; mi < 2; mi++)
#pragma unroll
        for (int kk = 0; kk < 2; kk++)
            qf[mi][kk] = *reinterpret_cast<const short8*>(
                &Qb[(size_t)(wq0 + mi * 16 + lr) * DKK + kk * 32 + lg * 8]);

    floatx4 oa[4][2] = {};                 // O^T accs: [dfrag f][qfrag mi]
    float m_s[2] = {-1e30f, -1e30f};
    float l_s[2] = {0.f, 0.f};

    const int nt = (q0 >> 6) + 4;          // covers kv0 < q0 + 256

    uint4 kr, vr;
    load_tile(&kr, &vr, Kb, Vb, 0, tid);

    for (int t = 0; t < nt; ++t) {
        const int kv0 = t << 6;
        const int cur = t & 1;
        store_tile(Kl[cur], Vl[cur], &kr, &vr, tid);
        __syncthreads();
        if (t + 1 < nt) load_tile(&kr, &vr, Kb, Vb, kv0 + KVB, tid);  // fly under compute

        if (kv0 < wq0 + 32) {
            // ---- S^T = K · Q : rows kv (lg*4+r), cols q (lr) ----
            floatx4 sa[4][2] = {};
            __builtin_amdgcn_s_setprio(1);
#pragma unroll
            for (int c = 0; c < 4; c++) {
                const int row = c * 16 + lr;
#pragma unroll
                for (int kk = 0; kk < 2; kk++) {
                    short8 kf = *reinterpret_cast<const short8*>(
                        &Kl[cur][row * 64 + (((kk * 4 + lg) ^ (lr & 7)) * 8)]);
#pragma unroll
                    for (int mi = 0; mi < 2; mi++)
                        sa[c][mi] = mfma16(kf, qf[mi][kk], sa[c][mi]);
                }
            }
            __builtin_amdgcn_s_setprio(0);
            const bool do_mask = (kv0 + KVB - 1 > wq0);
#pragma unroll
            for (int mi = 0; mi < 2; mi++) {
                const int q = wq0 + mi * 16 + lr;
                float pm = -1e30f;
#pragma unroll
                for (int c = 0; c < 4; c++)
#pragma unroll
                    for (int r = 0; r < 4; r++) {
                        float v = sa[c][mi][r];
                        if (do_mask && (kv0 + c * 16 + lg * 4 + r > q)) v = -1e30f;
                        sa[c][mi][r] = v;
                        pm = fmaxf(pm, v);
                    }
                pm = fmaxf(pm, __shfl_xor(pm, 16));
                pm = fmaxf(pm, __shfl_xor(pm, 32));
                const float mn = fmaxf(m_s[mi], pm);
                const float es = __expf(m_s[mi] - mn);
                m_s[mi] = mn;
                float ps = 0.f;
#pragma unroll
                for (int c = 0; c < 4; c++)
#pragma unroll
                    for (int r = 0; r < 4; r++) {
                        float p = __expf(sa[c][mi][r] - mn);
                        sa[c][mi][r] = p;
                        ps += p;
                    }
                ps += __shfl_xor(ps, 16);
                ps += __shfl_xor(ps, 32);
                l_s[mi] = l_s[mi] * es + ps;
#pragma unroll
                for (int f = 0; f < 4; f++)
#pragma unroll
                    for (int r = 0; r < 4; r++)
                        oa[f][mi][r] *= es;
                const int prow = mi * 16 + lr;
#pragma unroll
                for (int c = 0; c < 4; c++) {
                    uint2 pk;
                    pk.x = (unsigned)f2bf(sa[c][mi][0]) | ((unsigned)f2bf(sa[c][mi][1]) << 16);
                    pk.y = (unsigned)f2bf(sa[c][mi][2]) | ((unsigned)f2bf(sa[c][mi][3]) << 16);
                    *reinterpret_cast<uint2*>(
                        &Pl[w][prow * 64 + (((c * 2 + (lg >> 1)) ^ (lr & 7)) * 8) + (lg & 1) * 4]) = pk;
                }
            }
            // ---- O^T += V^T · P^T ----
            short8 pf[2][2];
#pragma unroll
            for (int mi = 0; mi < 2; mi++)
#pragma unroll
                for (int kk = 0; kk < 2; kk++)
                    pf[mi][kk] = *reinterpret_cast<const short8*>(
                        &Pl[w][(mi * 16 + lr) * 64 + (((kk * 4 + lg) ^ (lr & 7)) * 8)]);
            __builtin_amdgcn_s_setprio(1);
#pragma unroll
            for (int f = 0; f < 4; f++) {
                const int row = f * 16 + lr;
#pragma unroll
                for (int kk = 0; kk < 2; kk++) {
                    short8 vt = *reinterpret_cast<const short8*>(
                        &Vl[cur][row * 64 + (((kk * 4 + lg) ^ (lr & 7)) * 8)]);
#pragma unroll
                    for (int mi = 0; mi < 2; mi++)
                        oa[f][mi] = mfma16(vt, pf[mi][kk], oa[f][mi]);
                }
            }
            __builtin_amdgcn_s_setprio(0);
        }
        __syncthreads();
    }

    // ---- coalesced O epilogue: stage O^T into Pl[w] (swizzled), read back rows ----
#pragma unroll
    for (int mi = 0; mi < 2; mi++) {
        const float inv = 1.f / l_s[mi];
        const int prow = mi * 16 + lr;         // q-local row
#pragma unroll
        for (int f = 0; f < 4; f++) {
            uint2 pk;
            pk.x = (unsigned)f2bf(oa[f][mi][0] * inv) | ((unsigned)f2bf(oa[f][mi][1] * inv) << 16);
            pk.y = (unsigned)f2bf(oa[f][mi][2] * inv) | ((unsigned)f2bf(oa[f][mi][3] * inv) << 16);
            // d = f*16 + lg*4 + {0..3}; 16B slot = (f*2 + (lg>>1)) ^ (prow&7); half = lg&1
            *reinterpret_cast<uint2*>(
                &Pl[w][prow * 64 + (((f * 2 + (lg >> 1)) ^ (prow & 7)) * 8) + (lg & 1) * 4]) = pk;
        }
    }
    // read back: lane covers row rl = i*8 + (lane>>3), slot = lane&7 (deswizzled)
#pragma unroll
    for (int i = 0; i < 4; i++) {
        const int rl = i * 8 + (lane >> 3);
        const int slot = lane & 7;
        const uint4 o = *reinterpret_cast<const uint4*>(
            &Pl[w][rl * 64 + ((slot ^ (rl & 7)) * 8)]);
        const int q = wq0 + rl;
        *reinterpret_cast<uint4*>(
            &attn[((size_t)(b * SQL + q)) * DM + h * DKK + slot * 8]) = o;
    }
}

// ---------------- output projection, 128x64 tile: out = Attn @ Wo + bo (fp32) ----------------
__global__ __launch_bounds__(256) void proj_o2(
    const unsigned short* __restrict__ Attn, const unsigned short* __restrict__ WtO,
    const float* __restrict__ bo, float* __restrict__ out)
{
    __shared__ __align__(16) unsigned short As[128 * 64];
    __shared__ __align__(16) unsigned short Bs[64 * 64];

    const int tid = threadIdx.x;
    const int w = tid >> 6, lane = tid & 63;
    const int lg = lane >> 4, lr = lane & 15;
    const int wr = w >> 1, wc = w & 1;
    const int m0 = blockIdx.x * 128, n0 = blockIdx.y * 64;

    floatx4 acc[4][2] = {};

    int srow[4], scol[4], ldsoff[4];
#pragma unroll
    for (int i = 0; i < 4; i++) {
        const int idx = i * 256 + tid;
        srow[i] = idx >> 3;
        scol[i] = ((idx & 7) ^ (srow[i] & 7)) * 8;
        ldsoff[i] = (i * 256 + w * 64) * 8;
    }

    for (int k0 = 0; k0 < DM; k0 += 64) {
        __syncthreads();
#pragma unroll
        for (int i = 0; i < 4; i++)
            gload16(&Attn[(size_t)(m0 + srow[i]) * DM + k0 + scol[i]], &As[ldsoff[i]]);
#pragma unroll
        for (int i = 0; i < 2; i++)
            gload16(&WtO[(size_t)(n0 + srow[i]) * DM + k0 + scol[i]], &Bs[ldsoff[i]]);
        __syncthreads();
#pragma unroll
        for (int kk = 0; kk < 2; kk++) {
            short8 a[4], b[2];
#pragma unroll
            for (int mi = 0; mi < 4; mi++) {
                const int r = wr * 64 + mi * 16 + lr;
                a[mi] = *reinterpret_cast<const short8*>(&As[r * 64 + (((kk * 4 + lg) ^ (r & 7)) * 8)]);
            }
#pragma unroll
            for (int ni = 0; ni < 2; ni++) {
                const int r = wc * 32 + ni * 16 + lr;
                b[ni] = *reinterpret_cast<const short8*>(&Bs[r * 64 + (((kk * 4 + lg) ^ (r & 7)) * 8)]);
            }
#pragma unroll
            for (int mi = 0; mi < 4; mi++)
#pragma unroll
                for (int ni = 0; ni < 2; ni++)
                    acc[mi][ni] = mfma16(a[mi], b[ni], acc[mi][ni]);
        }
    }

#pragma unroll
    for (int mi = 0; mi < 4; mi++)
#pragma unroll
        for (int ni = 0; ni < 2; ni++)
#pragma unroll
            for (int r = 0; r < 4; r++) {
                const int m = m0 + wr * 64 + mi * 16 + lg * 4 + r;
                const int n = n0 + wc * 32 + ni * 16 + lr;
                out[(size_t)m * DM + n] = acc[mi][ni][r] + bo[n];
            }
}

extern "C" void kernel_launch(void* const* d_in, const int* in_sizes, int n_in,
                              void* d_out, int out_size, void* d_ws, size_t ws_size,
                              hipStream_t stream) {
    const float* query = (const float*)d_in[0];
    const float* key   = (const float*)d_in[1];
    const float* value = (const float*)d_in[2];
    const float* Wq = (const float*)d_in[4];
    const float* bq = (const float*)d_in[5];
    const float* Wk = (const float*)d_in[6];
    const float* bk = (const float*)d_in[7];
    const float* Wv = (const float*)d_in[8];
    const float* bv = (const float*)d_in[9];
    const float* Wo = (const float*)d_in[10];
    const float* bo = (const float*)d_in[11];
    float* out = (float*)d_out;

    unsigned short* ws = (unsigned short*)d_ws;
    const size_t MW = (size_t)DM * DM;            // 1M elems
    const size_t MH = (size_t)NB * NH * SQL * DKK; // 4.19M elems
    unsigned short* WtQ = ws;
    unsigned short* WtK = WtQ + MW;
    unsigned short* WtV = WtK + MW;
    unsigned short* WtO = WtV + MW;
    unsigned short* Qh  = WtO + MW;
    unsigned short* Kh  = Qh + MH;
    unsigned short* Vt  = Kh + MH;
    unsigned short* At  = Vt + MH;
    // scratch aliases (liveness-checked):
    //   Xbf_q, Xbf_k live in d_out (dead before proj_o2 writes out)
    //   Xbf_v aliases At (dead until attn_fwd writes At)
    unsigned short* Xbq = (unsigned short*)d_out;
    unsigned short* Xbk = Xbq + MH;
    unsigned short* Xbv = At;

    x2bf<<<2048, 256, 0, stream>>>(query, key, value, Xbq, Xbk, Xbv);
    transpose_w4<<<dim3(32, 32, 4), dim3(32, 8), 0, stream>>>(Wq, Wk, Wv, Wo, WtQ, WtK, WtV, WtO);
    proj_qkv2<<<dim3(32, 8, 3), 256, 0, stream>>>(Xbq, Xbk, Xbv, WtQ, WtK, WtV,
                                                  bq, bk, bv, Qh, Kh, Vt);
    attn_fwd<<<dim3(SQL / 256, NH, NB), 512, 0, stream>>>(Qh, Kh, Vt, At);
    proj_o2<<<dim3(32, 16), 256, 0, stream>>>(At, WtO, bo, out);
}

// Round 7
// 264.153 us; speedup vs baseline: 1.3502x; 1.0497x over previous
//
#include <hip/hip_runtime.h>
#include <hip/hip_bf16.h>

#define DM 1024
#define NH 16
#define DKK 64
#define NB 2
#define SQL 2048
#define SKL 2048

typedef __attribute__((ext_vector_type(8))) short short8;
typedef __attribute__((ext_vector_type(4))) float floatx4;

static __device__ inline floatx4 mfma16(short8 a, short8 b, floatx4 c) {
    return __builtin_amdgcn_mfma_f32_16x16x32_bf16(a, b, c, 0, 0, 0);
}

// native convert: compiler fuses pairs into v_cvt_pk_bf16_f32 (m240)
static __device__ inline unsigned short f2bf(float f) {
    __hip_bfloat16 h = __float2bfloat16(f);
    return *reinterpret_cast<unsigned short*>(&h);
}

// async global(16B/lane) -> LDS (linear, wave-uniform base + lane*16)
__device__ __forceinline__ void gload16(const void* g, void* l) {
    __builtin_amdgcn_global_load_lds(
        (const __attribute__((address_space(1))) void*)g,
        (__attribute__((address_space(3))) void*)l, 16, 0, 0);
}

// ---------------- fp32 -> bf16 conversion of Q/K/V inputs ----------------
__global__ __launch_bounds__(256) void x2bf(
    const float* __restrict__ q, const float* __restrict__ k, const float* __restrict__ v,
    unsigned short* __restrict__ oq, unsigned short* __restrict__ ok, unsigned short* __restrict__ ov)
{
    const int n4 = 1 << 20;  // float4s per input (B*S*DM/4)
    for (int i = blockIdx.x * blockDim.x + threadIdx.x; i < 3 * n4; i += gridDim.x * blockDim.x) {
        const int z = i >> 20, off = (i & (n4 - 1)) * 4;
        const float* src = z == 0 ? q : (z == 1 ? k : v);
        unsigned short* dst = z == 0 ? oq : (z == 1 ? ok : ov);
        const float4 f = *reinterpret_cast<const float4*>(&src[off]);
        uint2 p;
        p.x = (unsigned)f2bf(f.x) | ((unsigned)f2bf(f.y) << 16);
        p.y = (unsigned)f2bf(f.z) | ((unsigned)f2bf(f.w) << 16);
        *reinterpret_cast<uint2*>(&dst[off]) = p;
    }
}

// ---------------- weight transpose: Wt[n][k] = bf16(W[k][n]) ----------------
__global__ void transpose_w4(const float* __restrict__ Wq, const float* __restrict__ Wk,
                             const float* __restrict__ Wv, const float* __restrict__ Wo,
                             unsigned short* __restrict__ WtQ, unsigned short* __restrict__ WtK,
                             unsigned short* __restrict__ WtV, unsigned short* __restrict__ WtO) {
    const int z = blockIdx.z;
    const float* W = z == 0 ? Wq : (z == 1 ? Wk : (z == 2 ? Wv : Wo));
    unsigned short* Wt = z == 0 ? WtQ : (z == 1 ? WtK : (z == 2 ? WtV : WtO));
    __shared__ unsigned short t[32][33];
    int tx = threadIdx.x, ty = threadIdx.y; // block (32,8)
    int n0 = blockIdx.x * 32, k0 = blockIdx.y * 32;
#pragma unroll
    for (int i = 0; i < 4; i++) {
        int k = k0 + ty + i * 8;
        t[tx][ty + i * 8] = f2bf(W[k * DM + n0 + tx]);
    }
    __syncthreads();
#pragma unroll
    for (int i = 0; i < 4; i++) {
        int n = n0 + ty + i * 8;
        Wt[n * DM + k0 + tx] = t[ty + i * 8][tx];
    }
}

// ---------------- fused QKV projection, m97-style 128x128 tile ----------------
// C[m][n] = sum_k Xbf[m][k] * Wt[n][k] + bias[n]
// z==0: Q*0.125 -> [B,H,S,64]; z==1: K -> [B,H,S,64]; z==2: V -> [B,H,64,S]
__global__ __launch_bounds__(256) void proj_qkv2(
    const unsigned short* __restrict__ Xq, const unsigned short* __restrict__ Xk,
    const unsigned short* __restrict__ Xv,
    const unsigned short* __restrict__ WtQ, const unsigned short* __restrict__ WtK,
    const unsigned short* __restrict__ WtV,
    const float* __restrict__ bq, const float* __restrict__ bk, const float* __restrict__ bv,
    unsigned short* __restrict__ Qh, unsigned short* __restrict__ Kh, unsigned short* __restrict__ Vt)
{
    const int z = blockIdx.z;
    const unsigned short* X  = z == 0 ? Xq : (z == 1 ? Xk : Xv);
    const unsigned short* Wt = z == 0 ? WtQ : (z == 1 ? WtK : WtV);
    const float* bias = z == 0 ? bq : (z == 1 ? bk : bv);
    unsigned short* out = z == 0 ? Qh : (z == 1 ? Kh : Vt);

    __shared__ __align__(16) unsigned short As[128 * 64];
    __shared__ __align__(16) unsigned short Bs[128 * 64];

    const int tid = threadIdx.x;
    const int w = tid >> 6, lane = tid & 63;
    const int lg = lane >> 4, lr = lane & 15;
    const int wr = w >> 1, wc = w & 1;
    const int m0 = blockIdx.x * 128, n0 = blockIdx.y * 128;

    floatx4 acc[4][4] = {};

    int srow[4], scol[4], ldsoff[4];
#pragma unroll
    for (int i = 0; i < 4; i++) {
        const int idx = i * 256 + tid;
        srow[i] = idx >> 3;
        scol[i] = ((idx & 7) ^ (srow[i] & 7)) * 8;   // inverse-swizzled source col
        ldsoff[i] = (i * 256 + w * 64) * 8;          // wave-uniform, u16 units
    }

    for (int k0 = 0; k0 < DM; k0 += 64) {
        __syncthreads();
#pragma unroll
        for (int i = 0; i < 4; i++)
            gload16(&X[(size_t)(m0 + srow[i]) * DM + k0 + scol[i]], &As[ldsoff[i]]);
#pragma unroll
        for (int i = 0; i < 4; i++)
            gload16(&Wt[(size_t)(n0 + srow[i]) * DM + k0 + scol[i]], &Bs[ldsoff[i]]);
        __syncthreads();
#pragma unroll
        for (int kk = 0; kk < 2; kk++) {
            short8 a[4], b[4];
#pragma unroll
            for (int mi = 0; mi < 4; mi++) {
                const int r = wr * 64 + mi * 16 + lr;
                a[mi] = *reinterpret_cast<const short8*>(&As[r * 64 + (((kk * 4 + lg) ^ (r & 7)) * 8)]);
            }
#pragma unroll
            for (int ni = 0; ni < 4; ni++) {
                const int r = wc * 64 + ni * 16 + lr;
                b[ni] = *reinterpret_cast<const short8*>(&Bs[r * 64 + (((kk * 4 + lg) ^ (r & 7)) * 8)]);
            }
#pragma unroll
            for (int mi = 0; mi < 4; mi++)
#pragma unroll
                for (int ni = 0; ni < 4; ni++)
                    acc[mi][ni] = mfma16(a[mi], b[ni], acc[mi][ni]);
        }
    }

    const float qscale = (z == 0) ? 0.125f : 1.0f;
#pragma unroll
    for (int mi = 0; mi < 4; mi++)
#pragma unroll
        for (int ni = 0; ni < 4; ni++)
#pragma unroll
            for (int r = 0; r < 4; r++) {
                const int m = m0 + wr * 64 + mi * 16 + lg * 4 + r;
                const int n = n0 + wc * 64 + ni * 16 + lr;
                const float val = (acc[mi][ni][r] + bias[n]) * qscale;
                const int bb = m >> 11, s = m & 2047;
                const int h = n >> 6, d = n & 63;
                const unsigned short o = f2bf(val);
                if (z != 2)
                    out[(((size_t)(bb * NH + h) * SQL) + s) * DKK + d] = o;
                else
                    out[(((size_t)(bb * NH + h) * DKK) + d) * SKL + s] = o;
            }
}

// ---------------- causal flash attention ----------------
// QBLK=128 (8 waves x 16 q rows), 512 threads, grid = 512 blocks (all resident).
// KVB=64 double-buffered LDS, ONE barrier/tile, defer-max online softmax.
#define KVB 64

__device__ __forceinline__ void load_tile(uint4* kr, uint4* vr,
    const unsigned short* __restrict__ Kb, const unsigned short* __restrict__ Vb,
    int kv0, int tid)
{
    const int row = tid >> 3, sl = tid & 7;   // 512 threads: 64 rows x 8 slots
    *kr = *reinterpret_cast<const uint4*>(&Kb[(size_t)(kv0 + row) * DKK + sl * 8]);
    *vr = *reinterpret_cast<const uint4*>(&Vb[(size_t)row * SKL + kv0 + sl * 8]);
}

__device__ __forceinline__ void store_tile(unsigned short* kl, unsigned short* vl,
                                           const uint4* kr, const uint4* vr, int tid)
{
    const int row = tid >> 3, sl = tid & 7;
    const int off = row * 64 + ((sl ^ (row & 7)) * 8);
    *reinterpret_cast<uint4*>(&kl[off]) = *kr;
    *reinterpret_cast<uint4*>(&vl[off]) = *vr;
}

__global__ __launch_bounds__(512) void attn_fwd(
    const unsigned short* __restrict__ Qh, const unsigned short* __restrict__ Kh,
    const unsigned short* __restrict__ Vt, unsigned short* __restrict__ attn)
{
    __shared__ __align__(16) unsigned short Kl[2][4096];
    __shared__ __align__(16) unsigned short Vl[2][4096];
    __shared__ __align__(16) unsigned short Pl[8][1024];   // 16 rows x 64 per wave

    const int tid = threadIdx.x;
    const int w = tid >> 6, lane = tid & 63;
    const int lg = lane >> 4, lr = lane & 15;
    const int b = blockIdx.z, h = blockIdx.y;
    const int q0 = (int)(gridDim.x - 1 - blockIdx.x) * 128;  // big blocks first
    const int wq0 = q0 + w * 16;

    const unsigned short* Qb = Qh + (size_t)(b * NH + h) * SQL * DKK;
    const unsigned short* Kb = Kh + (size_t)(b * NH + h) * SKL * DKK;
    const unsigned short* Vb = Vt + (size_t)(b * NH + h) * DKK * SKL;

    short8 qf[2];
#pragma unroll
    for (int kk = 0; kk < 2; kk++)
        qf[kk] = *reinterpret_cast<const short8*>(
            &Qb[(size_t)(wq0 + lr) * DKK + kk * 32 + lg * 8]);

    floatx4 oa[4] = {};                    // O^T accs per d-frag
    float m_s = -1e30f, l_s = 0.f;

    const int nt = (q0 >> 6) + 2;          // covers kv0 <= q0 + 112

    uint4 kr, vr;
    load_tile(&kr, &vr, Kb, Vb, 0, tid);

    for (int t = 0; t < nt; ++t) {
        const int kv0 = t << 6;
        const int cur = t & 1;
        store_tile(Kl[cur], Vl[cur], &kr, &vr, tid);
        __syncthreads();                                   // one barrier per tile
        if (t + 1 < nt) load_tile(&kr, &vr, Kb, Vb, kv0 + KVB, tid);

        if (kv0 < wq0 + 16) {
            // ---- S^T = K · Q : per lane q=lr, kv = 16c + lg*4 + r ----
            floatx4 sa[4] = {};
            __builtin_amdgcn_s_setprio(1);
#pragma unroll
            for (int c = 0; c < 4; c++) {
                const int row = c * 16 + lr;
#pragma unroll
                for (int kk = 0; kk < 2; kk++) {
                    short8 kf = *reinterpret_cast<const short8*>(
                        &Kl[cur][row * 64 + (((kk * 4 + lg) ^ (lr & 7)) * 8)]);
                    sa[c] = mfma16(kf, qf[kk], sa[c]);
                }
            }
            __builtin_amdgcn_s_setprio(0);

            const bool do_mask = (kv0 + KVB - 1 > wq0);
            const int q = wq0 + lr;
            float pm = -1e30f;
#pragma unroll
            for (int c = 0; c < 4; c++)
#pragma unroll
                for (int r = 0; r < 4; r++) {
                    float v = sa[c][r];
                    if (do_mask && (kv0 + c * 16 + lg * 4 + r > q)) v = -1e30f;
                    sa[c][r] = v;
                    pm = fmaxf(pm, v);
                }
            pm = fmaxf(pm, __shfl_xor(pm, 16));
            pm = fmaxf(pm, __shfl_xor(pm, 32));
            // defer-max (T13): only rescale when max grew by > 8
            if (!__all(pm <= m_s + 8.f)) {
                const float mn = fmaxf(m_s, pm);
                const float es = __expf(m_s - mn);
                m_s = mn;
                l_s *= es;
#pragma unroll
                for (int f = 0; f < 4; f++)
#pragma unroll
                    for (int r = 0; r < 4; r++)
                        oa[f][r] *= es;
            }
            float ps = 0.f;
#pragma unroll
            for (int c = 0; c < 4; c++)
#pragma unroll
                for (int r = 0; r < 4; r++) {
                    float p = __expf(sa[c][r] - m_s);
                    sa[c][r] = p;
                    ps += p;
                }
            ps += __shfl_xor(ps, 16);
            ps += __shfl_xor(ps, 32);
            l_s += ps;
            // write P row lr, kv = 16c + lg*4 + r (swizzled 16B slots)
#pragma unroll
            for (int c = 0; c < 4; c++) {
                uint2 pk;
                pk.x = (unsigned)f2bf(sa[c][0]) | ((unsigned)f2bf(sa[c][1]) << 16);
                pk.y = (unsigned)f2bf(sa[c][2]) | ((unsigned)f2bf(sa[c][3]) << 16);
                *reinterpret_cast<uint2*>(
                    &Pl[w][lr * 64 + (((c * 2 + (lg >> 1)) ^ (lr & 7)) * 8) + (lg & 1) * 4]) = pk;
            }
            // ---- O^T += V^T · P^T ----
            short8 pf[2];
#pragma unroll
            for (int kk = 0; kk < 2; kk++)
                pf[kk] = *reinterpret_cast<const short8*>(
                    &Pl[w][lr * 64 + (((kk * 4 + lg) ^ (lr & 7)) * 8)]);
            __builtin_amdgcn_s_setprio(1);
#pragma unroll
            for (int f = 0; f < 4; f++) {
                const int row = f * 16 + lr;
#pragma unroll
                for (int kk = 0; kk < 2; kk++) {
                    short8 vt = *reinterpret_cast<const short8*>(
                        &Vl[cur][row * 64 + (((kk * 4 + lg) ^ (lr & 7)) * 8)]);
                    oa[f] = mfma16(vt, pf[kk], oa[f]);
                }
            }
            __builtin_amdgcn_s_setprio(0);
        }
    }

    // ---- coalesced O epilogue: stage O^T into Pl[w] (swizzled), read back rows ----
    {
        const float inv = 1.f / l_s;
#pragma unroll
        for (int f = 0; f < 4; f++) {
            uint2 pk;
            pk.x = (unsigned)f2bf(oa[f][0] * inv) | ((unsigned)f2bf(oa[f][1] * inv) << 16);
            pk.y = (unsigned)f2bf(oa[f][2] * inv) | ((unsigned)f2bf(oa[f][3] * inv) << 16);
            *reinterpret_cast<uint2*>(
                &Pl[w][lr * 64 + (((f * 2 + (lg >> 1)) ^ (lr & 7)) * 8) + (lg & 1) * 4]) = pk;
        }
    }
#pragma unroll
    for (int i = 0; i < 2; i++) {
        const int rl = i * 8 + (lane >> 3);
        const int slot = lane & 7;
        const uint4 o = *reinterpret_cast<const uint4*>(
            &Pl[w][rl * 64 + ((slot ^ (rl & 7)) * 8)]);
        const int q = wq0 + rl;
        *reinterpret_cast<uint4*>(
            &attn[((size_t)(b * SQL + q)) * DM + h * DKK + slot * 8]) = o;
    }
}

// ---------------- output projection, 128x64 tile: out = Attn @ Wo + bo (fp32) ----------------
__global__ __launch_bounds__(256) void proj_o2(
    const unsigned short* __restrict__ Attn, const unsigned short* __restrict__ WtO,
    const float* __restrict__ bo, float* __restrict__ out)
{
    __shared__ __align__(16) unsigned short As[128 * 64];
    __shared__ __align__(16) unsigned short Bs[64 * 64];

    const int tid = threadIdx.x;
    const int w = tid >> 6, lane = tid & 63;
    const int lg = lane >> 4, lr = lane & 15;
    const int wr = w >> 1, wc = w & 1;
    const int m0 = blockIdx.x * 128, n0 = blockIdx.y * 64;

    floatx4 acc[4][2] = {};

    int srow[4], scol[4], ldsoff[4];
#pragma unroll
    for (int i = 0; i < 4; i++) {
        const int idx = i * 256 + tid;
        srow[i] = idx >> 3;
        scol[i] = ((idx & 7) ^ (srow[i] & 7)) * 8;
        ldsoff[i] = (i * 256 + w * 64) * 8;
    }

    for (int k0 = 0; k0 < DM; k0 += 64) {
        __syncthreads();
#pragma unroll
        for (int i = 0; i < 4; i++)
            gload16(&Attn[(size_t)(m0 + srow[i]) * DM + k0 + scol[i]], &As[ldsoff[i]]);
#pragma unroll
        for (int i = 0; i < 2; i++)
            gload16(&WtO[(size_t)(n0 + srow[i]) * DM + k0 + scol[i]], &Bs[ldsoff[i]]);
        __syncthreads();
#pragma unroll
        for (int kk = 0; kk < 2; kk++) {
            short8 a[4], b[2];
#pragma unroll
            for (int mi = 0; mi < 4; mi++) {
                const int r = wr * 64 + mi * 16 + lr;
                a[mi] = *reinterpret_cast<const short8*>(&As[r * 64 + (((kk * 4 + lg) ^ (r & 7)) * 8)]);
            }
#pragma unroll
            for (int ni = 0; ni < 2; ni++) {
                const int r = wc * 32 + ni * 16 + lr;
                b[ni] = *reinterpret_cast<const short8*>(&Bs[r * 64 + (((kk * 4 + lg) ^ (r & 7)) * 8)]);
            }
#pragma unroll
            for (int mi = 0; mi < 4; mi++)
#pragma unroll
                for (int ni = 0; ni < 2; ni++)
                    acc[mi][ni] = mfma16(a[mi], b[ni], acc[mi][ni]);
        }
    }

#pragma unroll
    for (int mi = 0; mi < 4; mi++)
#pragma unroll
        for (int ni = 0; ni < 2; ni++)
#pragma unroll
            for (int r = 0; r < 4; r++) {
                const int m = m0 + wr * 64 + mi * 16 + lg * 4 + r;
                const int n = n0 + wc * 32 + ni * 16 + lr;
                out[(size_t)m * DM + n] = acc[mi][ni][r] + bo[n];
            }
}

extern "C" void kernel_launch(void* const* d_in, const int* in_sizes, int n_in,
                              void* d_out, int out_size, void* d_ws, size_t ws_size,
                              hipStream_t stream) {
    const float* query = (const float*)d_in[0];
    const float* key   = (const float*)d_in[1];
    const float* value = (const float*)d_in[2];
    const float* Wq = (const float*)d_in[4];
    const float* bq = (const float*)d_in[5];
    const float* Wk = (const float*)d_in[6];
    const float* bk = (const float*)d_in[7];
    const float* Wv = (const float*)d_in[8];
    const float* bv = (const float*)d_in[9];
    const float* Wo = (const float*)d_in[10];
    const float* bo = (const float*)d_in[11];
    float* out = (float*)d_out;

    unsigned short* ws = (unsigned short*)d_ws;
    const size_t MW = (size_t)DM * DM;            // 1M elems
    const size_t MH = (size_t)NB * NH * SQL * DKK; // 4.19M elems
    unsigned short* WtQ = ws;
    unsigned short* WtK = WtQ + MW;
    unsigned short* WtV = WtK + MW;
    unsigned short* WtO = WtV + MW;
    unsigned short* Qh  = WtO + MW;
    unsigned short* Kh  = Qh + MH;
    unsigned short* Vt  = Kh + MH;
    unsigned short* At  = Vt + MH;
    // scratch aliases (liveness-checked):
    //   Xbf_q, Xbf_k live in d_out (dead before proj_o2 writes out)
    //   Xbf_v aliases At (dead until attn_fwd writes At)
    unsigned short* Xbq = (unsigned short*)d_out;
    unsigned short* Xbk = Xbq + MH;
    unsigned short* Xbv = At;

    x2bf<<<2048, 256, 0, stream>>>(query, key, value, Xbq, Xbk, Xbv);
    transpose_w4<<<dim3(32, 32, 4), dim3(32, 8), 0, stream>>>(Wq, Wk, Wv, Wo, WtQ, WtK, WtV, WtO);
    proj_qkv2<<<dim3(32, 8, 3), 256, 0, stream>>>(Xbq, Xbk, Xbv, WtQ, WtK, WtV,
                                                  bq, bk, bv, Qh, Kh, Vt);
    attn_fwd<<<dim3(SQL / 128, NH, NB), 512, 0, stream>>>(Qh, Kh, Vt, At);
    proj_o2<<<dim3(32, 16), 256, 0, stream>>>(At, WtO, bo, out);
}